// Round 7
// baseline (297.566 us; speedup 1.0000x reference)
//
#include <hip/hip_runtime.h>
#include <cstddef>

// Problem dims (fixed by setup_inputs)
#define Mdim 256     // batch B
#define Ndim 2048    // neurons N
#define Kdim 2048    // K (= N, W is NxN)
#define Tsteps 128   // time steps

typedef float v4f __attribute__((ext_vector_type(4)));

// ws layout: [0,256)   = tile-nonzero flags (byte[c*16+g])
//            [4096, +2MB) = I table (Mdim x Ndim fp32)

// ---------------------------------------------------------------------------
// Kernel 1: scan W -> 256-byte tile-nonzero bitmap.
// flags byte[c*16 + g]: bit i set iff tile (kt = g*8+i, column c) nonzero.
// Grid (16 c, 16 g), 256 threads; one byte per block, single writer.
// ---------------------------------------------------------------------------
__global__ __launch_bounds__(256) void scan_w_kernel(
    const float* __restrict__ W, unsigned char* __restrict__ flags)
{
    const int c = blockIdx.x;   // column group (n / 128)
    const int g = blockIdx.y;   // k-tile group (kt / 8)
    const int tid = threadIdx.x;

    __shared__ int wmask[4];

    const int coff = (tid & 31) * 4;       // 0..124
    const int rbase = tid >> 5;            // 0..7

    unsigned mask = 0;
#pragma unroll
    for (int it = 0; it < 16; ++it) {
        const int r = it * 8 + rbase;      // 0..127, tile bit = it>>1
        const float4 v = *(const float4*)&W[(size_t)(g * 128 + r) * Ndim + c * 128 + coff];
        const bool nz = (v.x != 0.0f) | (v.y != 0.0f) | (v.z != 0.0f) | (v.w != 0.0f);
        mask |= (nz ? 1u : 0u) << (it >> 1);
    }
#pragma unroll
    for (int off = 32; off; off >>= 1) mask |= __shfl_down(mask, off);
    if ((tid & 63) == 0) wmask[tid >> 6] = (int)mask;
    __syncthreads();
    if (tid == 0) {
        const int m = wmask[0] | wmask[1] | wmask[2] | wmask[3];
        flags[c * 16 + g] = (unsigned char)m;
    }
}

// ---------------------------------------------------------------------------
// Kernel 2: flagged GEMM -> I table.  I[b,n] = sum over FLAGGED k-tiles of
// x[b,k]*W[k,n], ascending k (skipped tiles contribute exactly +/-0; for the
// identity-W benchmark input this is bit-exact for any tile subset).
// Grid (16 c, 16 mb), 256 threads: thread owns 1 n and 8 b's.
// W-band reads are L2/L3-hot (scanned by K1); x reads are wave-uniform
// (scalar loads). EVERY I element is written (ws arrives poisoned).
// ---------------------------------------------------------------------------
__global__ __launch_bounds__(256) void gemm_flagged_kernel(
    const float* __restrict__ x, const float* __restrict__ W,
    const unsigned* __restrict__ flags, float* __restrict__ I)
{
    const int c  = blockIdx.x;                 // n / 128
    const int mb = blockIdx.y;                 // b / 16
    const int tid = threadIdx.x;
    const int n  = c * 128 + (tid & 127);
    const int b0 = mb * 16 + (tid >> 7) * 8;   // 8 consecutive batch rows

    float f[8];
#pragma unroll
    for (int i = 0; i < 8; ++i) f[i] = 0.0f;

#pragma unroll
    for (int w = 0; w < 4; ++w) {
        unsigned word = flags[c * 4 + w];      // bits kt = w*32 + bit
        while (word) {
            const int bit = __builtin_ctz(word);
            word &= word - 1;
            const int k0 = (w * 32 + bit) * 16;
            const float* wp = W + (size_t)k0 * Ndim + n;
            const float* xp = x + k0;
#pragma unroll
            for (int kk = 0; kk < 16; ++kk) {
                const float wv = wp[(size_t)kk * Ndim];       // coalesced
#pragma unroll
                for (int i = 0; i < 8; ++i)                   // x: wave-uniform
                    f[i] = fmaf(xp[(size_t)(b0 + i) * Kdim + kk], wv, f[i]);
            }
        }
    }
#pragma unroll
    for (int i = 0; i < 8; ++i)
        I[(size_t)(b0 + i) * Ndim + n] = f[i];   // unconditional: kills poison
}

// ---------------------------------------------------------------------------
// Kernel 3: LIF rollout, stores INTERLEAVED into the recurrence.  The write
// phase is HBM-BW-bound (~43 us) with most VALU issue slots idle; firing the
// nontemporal store of step t right after computing it hides the whole
// recurrence (~5 us of VALU) inside the BW drain (stores need no waitcnt).
//   V_{t+1} = (ALPHA*V_t + I) * (1 - Z_t);  Z_{t+1} = (V_{t+1} >= 1)
// __fmul_rn/__fadd_rn forbid FMA contraction -> bit-match numpy's mul+add.
// ---------------------------------------------------------------------------
__global__ __launch_bounds__(256, 2) void lif_sim_kernel(
    const float* __restrict__ I, float* __restrict__ out)
{
    const int tid = threadIdx.x;
    const int b = blockIdx.x >> 1;                        // uniform per block
    const int n = ((blockIdx.x & 1) << 10) + tid * 4;     // 0..2047

    const float4 I4 = *(const float4*)&I[(size_t)b * Ndim + n];  // L2/L3-hot
    const float Iv[4] = {I4.x, I4.y, I4.z, I4.w};

    // fp32(exp(-0.1) computed in f64) — matches numpy scalar promotion
    const float ALPHA = (float)0.9048374180359595;

    float V[4] = {0.0f, 0.0f, 0.0f, 0.0f};
    float Z[4] = {0.0f, 0.0f, 0.0f, 0.0f};

    float* op = out + (size_t)b * Tsteps * Ndim + n;
#pragma unroll 8
    for (int t = 0; t < Tsteps; ++t) {
#pragma unroll
        for (int j = 0; j < 4; ++j) {
            float v = __fmul_rn(ALPHA, V[j]);          // ALPHA * V
            v = __fadd_rn(v, Iv[j]);                   // + I
            v = __fmul_rn(v, __fsub_rn(1.0f, Z[j]));   // * (1 - Z_prev)
            V[j] = v;
            Z[j] = (v >= 1.0f) ? 1.0f : 0.0f;
        }
        v4f s = {Z[0], Z[1], Z[2], Z[3]};
        __builtin_nontemporal_store(s, (v4f*)(op + (size_t)t * Ndim));
    }
}

// ---------------------------------------------------------------------------
extern "C" void kernel_launch(void* const* d_in, const int* in_sizes, int n_in,
                              void* d_out, int out_size, void* d_ws, size_t ws_size,
                              hipStream_t stream) {
    const float* x = (const float*)d_in[0];   // [256, 2048] fp32
    const float* W = (const float*)d_in[1];   // [2048, 2048] fp32
    float* out = (float*)d_out;               // [256, 128, 2048] fp32

    unsigned char* flags = (unsigned char*)d_ws;            // 256 bytes
    float* I = (float*)((char*)d_ws + 4096);                // 2 MB table

    scan_w_kernel<<<dim3(16, 16), 256, 0, stream>>>(W, flags);

    gemm_flagged_kernel<<<dim3(16, 16), 256, 0, stream>>>(
        x, W, (const unsigned*)flags, I);

    const int sim_blocks = Mdim * Ndim / 1024;              // 512
    lif_sim_kernel<<<dim3(sim_blocks), 256, 0, stream>>>(I, out);
}

// Round 8
// 286.834 us; speedup vs baseline: 1.0374x; 1.0374x over previous
//
#include <hip/hip_runtime.h>
#include <cstddef>

// Problem dims (fixed by setup_inputs)
#define Mdim 256     // batch B
#define Ndim 2048    // neurons N
#define Kdim 2048    // K (= N, W is NxN)
#define Tsteps 128   // time steps

typedef float v4f __attribute__((ext_vector_type(4)));

// ---------------------------------------------------------------------------
// Kernel 1: scan W -> 256-byte tile-nonzero bitmap in ws.
// flags byte[c*16 + g]: bit i set iff tile (kt = g*8+i, column c) nonzero.
// Grid (16 c, 16 g), 256 threads; one byte per block, single writer -> no
// init, no atomics (ws arrives poisoned).
// ---------------------------------------------------------------------------
__global__ __launch_bounds__(256) void scan_w_kernel(
    const float* __restrict__ W, unsigned char* __restrict__ flags)
{
    const int c = blockIdx.x;   // column group (n / 128)
    const int g = blockIdx.y;   // k-tile group (kt / 8)
    const int tid = threadIdx.x;

    __shared__ int wmask[4];

    const int coff = (tid & 31) * 4;       // 0..124
    const int rbase = tid >> 5;            // 0..7

    unsigned mask = 0;
#pragma unroll
    for (int it = 0; it < 16; ++it) {
        const int r = it * 8 + rbase;      // 0..127, tile bit = it>>1
        const float4 v = *(const float4*)&W[(size_t)(g * 128 + r) * Ndim + c * 128 + coff];
        const bool nz = (v.x != 0.0f) | (v.y != 0.0f) | (v.z != 0.0f) | (v.w != 0.0f);
        mask |= (nz ? 1u : 0u) << (it >> 1);
    }
#pragma unroll
    for (int off = 32; off; off >>= 1) mask |= __shfl_down(mask, off);
    if ((tid & 63) == 0) wmask[tid >> 6] = (int)mask;
    __syncthreads();
    if (tid == 0) {
        const int m = wmask[0] | wmask[1] | wmask[2] | wmask[3];
        flags[c * 16 + g] = (unsigned char)m;
    }
}

// ---------------------------------------------------------------------------
// Kernel 2: fused current + LIF rollout (best-measured R6 structure).
// Phase A: I[b,n] over FLAGGED W k-tiles only (skipped tiles contribute
//          exactly +/-0 -> spikes unaffected; W band is L2-hot after K1).
// Phase B: 128-step recurrence, spikes packed into 16 u32 regs (no stores,
//          no memory dependence).
//   V_{t+1} = (ALPHA*V_t + I) * (1 - Z_t);  Z_{t+1} = (V_{t+1} >= 1)
//   __fmul_rn/__fadd_rn forbid FMA contraction -> bit-match numpy's mul+add.
// Phase C: natural-order streaming write of 268 MB. All 128 stores are
//          independent of each other and of any later instruction
//          (fire-and-forget nontemporal) -> max outstanding stores, zero
//          swizzle VALU. This phase is HBM-write-BW-bound (~42 us).
// ---------------------------------------------------------------------------
__global__ __launch_bounds__(256, 2) void lif_fused_kernel(
    const float* __restrict__ x, const float* __restrict__ W,
    const unsigned* __restrict__ flags, float* __restrict__ out)
{
    __shared__ float xs[Kdim];   // 8 KB: this block's x row

    const int tid = threadIdx.x;
    const int b = blockIdx.x >> 1;                        // uniform per block
    const int n = ((blockIdx.x & 1) << 10) + tid * 4;     // 0..2047
    const int c = n >> 7;                                 // flag column

    // stage x[b,:] -> LDS
    {
        const float* xp = x + (size_t)b * Kdim;
        *(float4*)&xs[tid * 4]        = *(const float4*)&xp[tid * 4];
        *(float4*)&xs[1024 + tid * 4] = *(const float4*)&xp[1024 + tid * 4];
    }
    __syncthreads();

    // ---- Phase A: dot over flagged k-tiles, ascending kt ----
    float f0 = 0.0f, f1 = 0.0f, f2 = 0.0f, f3 = 0.0f;
#pragma unroll
    for (int w = 0; w < 4; ++w) {
        unsigned word = flags[c * 4 + w];   // bits kt = w*32 + bit
        while (word) {
            const int bit = __builtin_ctz(word);
            word &= word - 1;
            const int k0 = (w * 32 + bit) * 16;
            const float* wp = W + (size_t)k0 * Ndim + n;
#pragma unroll
            for (int kk = 0; kk < 16; ++kk) {
                const float xv = xs[k0 + kk];                    // LDS broadcast
                const float4 wv = *(const float4*)(wp + (size_t)kk * Ndim);
                f0 = fmaf(xv, wv.x, f0);
                f1 = fmaf(xv, wv.y, f1);
                f2 = fmaf(xv, wv.z, f2);
                f3 = fmaf(xv, wv.w, f3);
            }
        }
    }
    const float Iv[4] = {f0, f1, f2, f3};

    // fp32(exp(-0.1) computed in f64) — matches numpy scalar promotion
    const float ALPHA = (float)0.9048374180359595;

    // ---- Phase B: recurrence, pack spikes into bits (no stores) ----
    unsigned zb[4][4] = {{0u, 0u, 0u, 0u}, {0u, 0u, 0u, 0u},
                         {0u, 0u, 0u, 0u}, {0u, 0u, 0u, 0u}};
    float V[4] = {0.0f, 0.0f, 0.0f, 0.0f};
    float Z[4] = {0.0f, 0.0f, 0.0f, 0.0f};
#pragma unroll
    for (int w = 0; w < 4; ++w) {
#pragma unroll
        for (int t2 = 0; t2 < 32; ++t2) {
#pragma unroll
            for (int j = 0; j < 4; ++j) {
                float v = __fmul_rn(ALPHA, V[j]);          // ALPHA * V
                v = __fadd_rn(v, Iv[j]);                   // + I
                v = __fmul_rn(v, __fsub_rn(1.0f, Z[j]));   // * (1 - Z_prev)
                V[j] = v;
                const bool sp = (v >= 1.0f);
                Z[j] = sp ? 1.0f : 0.0f;
                zb[j][w] |= sp ? (1u << t2) : 0u;
            }
        }
    }

    // ---- Phase C: natural-order streaming write (all stores independent) ----
    float* op = out + (size_t)b * Tsteps * Ndim + n;
#pragma unroll
    for (int w = 0; w < 4; ++w) {
#pragma unroll
        for (int t2 = 0; t2 < 32; ++t2) {
            v4f s = { (float)((zb[0][w] >> t2) & 1u),
                      (float)((zb[1][w] >> t2) & 1u),
                      (float)((zb[2][w] >> t2) & 1u),
                      (float)((zb[3][w] >> t2) & 1u) };
            __builtin_nontemporal_store(s, (v4f*)(op + (size_t)(w * 32 + t2) * Ndim));
        }
    }
}

// ---------------------------------------------------------------------------
extern "C" void kernel_launch(void* const* d_in, const int* in_sizes, int n_in,
                              void* d_out, int out_size, void* d_ws, size_t ws_size,
                              hipStream_t stream) {
    const float* x = (const float*)d_in[0];   // [256, 2048] fp32
    const float* W = (const float*)d_in[1];   // [2048, 2048] fp32
    float* out = (float*)d_out;               // [256, 128, 2048] fp32

    unsigned char* flags = (unsigned char*)d_ws;   // 256 bytes used

    scan_w_kernel<<<dim3(16, 16), 256, 0, stream>>>(W, flags);

    const int sim_blocks = Mdim * Ndim / 1024;     // 512
    lif_fused_kernel<<<dim3(sim_blocks), 256, 0, stream>>>(
        x, W, (const unsigned*)flags, out);
}